// Round 1
// baseline (1086.538 us; speedup 1.0000x reference)
//
#include <hip/hip_runtime.h>

#define N_NODES 100000
#define N_EDGES 1200000
#define DIM 64

// One thread per (edge, feature). Wave-uniform edge index -> scalar loads for
// src/dst; the 64 lanes of a wave cover one edge's contiguous feature row.
__global__ __launch_bounds__(256) void scatter_kernel(
    const float* __restrict__ feat,
    const int* __restrict__ src,
    const int* __restrict__ dst,
    float* __restrict__ agg,
    float* __restrict__ cnt,
    int doCnt) {
    long long idx = (long long)blockIdx.x * blockDim.x + threadIdx.x;
    long long total = (long long)N_EDGES * DIM;
    if (idx >= total) return;
    int e = (int)(idx >> 6);
    int d = (int)(idx & 63);
    int s = src[e];
    int t = dst[e];
    atomicAdd(&agg[(long long)t * DIM + d], feat[(long long)s * DIM + d]);
    if (doCnt && d == 0) atomicAdd(&cnt[t], 1.0f);
}

// One wave per node; lane j computes output feature j.
// out[n][j] = act( b[j] + sum_k mean[n][k]*Wl[k][j] + sum_k h[n][k]*Wr[k][j] )
template <int LAYER>
__global__ __launch_bounds__(256) void combine_kernel(
    const float* __restrict__ agg,
    const float* __restrict__ cnt,
    const float* __restrict__ hin,
    const float* __restrict__ Wl,
    const float* __restrict__ Wr,
    const float* __restrict__ b,
    const float* __restrict__ u1,
    float* __restrict__ out) {
    __shared__ float sWl[DIM * DIM];
    __shared__ float sWr[DIM * DIM];
    for (int i = threadIdx.x; i < DIM * DIM; i += blockDim.x) {
        sWl[i] = Wl[i];
        sWr[i] = Wr[i];
    }
    __syncthreads();

    const int lane = threadIdx.x & 63;
    const int waveInBlock = threadIdx.x >> 6;
    const int wavesPerBlock = blockDim.x >> 6;
    const int nWaves = gridDim.x * wavesPerBlock;
    int wave = blockIdx.x * wavesPerBlock + waveInBlock;

    const float bj = b[lane];

    for (int n = wave; n < N_NODES; n += nWaves) {
        const long long base = (long long)n * DIM;
        float c = cnt[n];
        float inv = 1.0f / fmaxf(c, 1.0f);
        float mean_j = agg[base + lane] * inv;
        float h_j = hin[base + lane];
        float acc = bj;
#pragma unroll
        for (int k = 0; k < DIM; ++k) {
            float mk = __shfl(mean_j, k, 64);
            float hk = __shfl(h_j, k, 64);
            acc += mk * sWl[k * DIM + lane];
            acc += hk * sWr[k * DIM + lane];
        }
        acc = fmaxf(acc, 0.0f);  // ReLU
        if (LAYER == 1) {
            // dropout: mask = (u > 0.5) / 0.5
            float u = u1[base + lane];
            acc = (u > 0.5f) ? acc * 2.0f : 0.0f;
        }
        out[base + lane] = acc;
    }
}

extern "C" void kernel_launch(void* const* d_in, const int* in_sizes, int n_in,
                              void* d_out, int out_size, void* d_ws, size_t ws_size,
                              hipStream_t stream) {
    const float* x   = (const float*)d_in[0];
    const int*   ei  = (const int*)d_in[1];   // int32 on device (jax x64 off)
    const float* u1  = (const float*)d_in[2];
    const float* W1l = (const float*)d_in[3];
    const float* W1r = (const float*)d_in[4];
    const float* b1  = (const float*)d_in[5];
    const float* W2l = (const float*)d_in[6];
    const float* W2r = (const float*)d_in[7];
    const float* b2  = (const float*)d_in[8];
    float* out = (float*)d_out;

    const int* src = ei;             // edge_index[0]
    const int* dst = ei + N_EDGES;   // edge_index[1]

    // Workspace layout (ws re-poisoned to 0xAA before every launch):
    char* ws = (char*)d_ws;
    float* cnt = (float*)ws;                                     // N floats
    size_t off = ((size_t)N_NODES * sizeof(float) + 255) & ~(size_t)255;
    float* agg = (float*)(ws + off);                             // N*64 floats
    float* h1  = agg + (size_t)N_NODES * DIM;                    // N*64 floats

    const size_t aggBytes = (size_t)N_NODES * DIM * sizeof(float);

    hipMemsetAsync(cnt, 0, (size_t)N_NODES * sizeof(float), stream);
    hipMemsetAsync(agg, 0, aggBytes, stream);

    const long long totalSc = (long long)N_EDGES * DIM;
    const int scBlocks = (int)((totalSc + 255) / 256);
    const int cbBlocks = 2048;

    // ---- Layer 1 ----
    scatter_kernel<<<scBlocks, 256, 0, stream>>>(x, src, dst, agg, cnt, 1);
    combine_kernel<1><<<cbBlocks, 256, 0, stream>>>(agg, cnt, x, W1l, W1r, b1, u1, h1);

    // ---- Layer 2 ----
    hipMemsetAsync(agg, 0, aggBytes, stream);
    scatter_kernel<<<scBlocks, 256, 0, stream>>>(h1, src, dst, agg, cnt, 0);
    combine_kernel<2><<<cbBlocks, 256, 0, stream>>>(agg, cnt, h1, W2l, W2r, b2, nullptr, out);
}

// Round 2
// 838.575 us; speedup vs baseline: 1.2957x; 1.2957x over previous
//
#include <hip/hip_runtime.h>

#define N_NODES 100000
#define N_EDGES 1200000
#define DIM 64
#define NB_SCAN ((N_NODES + 255) / 256)   // 391

// ---------- counting sort of edges by dst ----------

__global__ __launch_bounds__(256) void hist_kernel(const int* __restrict__ dst,
                                                   int* __restrict__ cnt) {
    int e = blockIdx.x * blockDim.x + threadIdx.x;
    if (e < N_EDGES) atomicAdd(&cnt[dst[e]], 1);
}

// per-256-block exclusive scan; emits block totals
__global__ __launch_bounds__(256) void scan_block_kernel(const int* __restrict__ cnt,
                                                         int* __restrict__ excl,
                                                         int* __restrict__ bsum) {
    __shared__ int tmp[256];
    int gid = blockIdx.x * 256 + threadIdx.x;
    int v = (gid < N_NODES) ? cnt[gid] : 0;
    tmp[threadIdx.x] = v;
    __syncthreads();
    for (int ofs = 1; ofs < 256; ofs <<= 1) {
        int t = (threadIdx.x >= ofs) ? tmp[threadIdx.x - ofs] : 0;
        __syncthreads();
        tmp[threadIdx.x] += t;
        __syncthreads();
    }
    if (gid < N_NODES) excl[gid] = tmp[threadIdx.x] - v;
    if (threadIdx.x == 255) bsum[blockIdx.x] = tmp[255];
}

// single-block exclusive scan of the block totals (NB_SCAN <= 512)
__global__ __launch_bounds__(512) void scan_sums_kernel(int* __restrict__ bsum) {
    __shared__ int tmp[512];
    int v = (threadIdx.x < NB_SCAN) ? bsum[threadIdx.x] : 0;
    tmp[threadIdx.x] = v;
    __syncthreads();
    for (int ofs = 1; ofs < 512; ofs <<= 1) {
        int t = (threadIdx.x >= ofs) ? tmp[threadIdx.x - ofs] : 0;
        __syncthreads();
        tmp[threadIdx.x] += t;
        __syncthreads();
    }
    if (threadIdx.x < NB_SCAN) bsum[threadIdx.x] = tmp[threadIdx.x] - v;
}

__global__ __launch_bounds__(256) void scan_add_kernel(int* __restrict__ excl,
                                                       const int* __restrict__ bsum) {
    int gid = blockIdx.x * 256 + threadIdx.x;
    if (gid < N_NODES) excl[gid] += bsum[blockIdx.x];
}

__global__ __launch_bounds__(256) void reorder_kernel(const int* __restrict__ src,
                                                      const int* __restrict__ dst,
                                                      const int* __restrict__ off,
                                                      int* __restrict__ cursor,
                                                      int* __restrict__ ssrc) {
    int e = blockIdx.x * blockDim.x + threadIdx.x;
    if (e < N_EDGES) {
        int t = dst[e];
        int p = off[t] + atomicAdd(&cursor[t], 1);
        ssrc[p] = src[e];
    }
}

// ---------- fused: mean-aggregate + (mean@Wl + h@Wr + b) + ReLU (+dropout) ----------
// One wave per node; lane j owns feature j.
template <int LAYER>
__global__ __launch_bounds__(256) void sage_fused(
    const float* __restrict__ h,
    const int* __restrict__ ssrc,
    const int* __restrict__ off,
    const int* __restrict__ cnt,
    const float* __restrict__ Wl,
    const float* __restrict__ Wr,
    const float* __restrict__ bias,
    const float* __restrict__ u1,
    float* __restrict__ out) {
    __shared__ float sWl[DIM * DIM];
    __shared__ float sWr[DIM * DIM];
    for (int i = threadIdx.x; i < DIM * DIM; i += blockDim.x) {
        sWl[i] = Wl[i];
        sWr[i] = Wr[i];
    }
    __syncthreads();

    const int lane = threadIdx.x & 63;
    const int wave = (blockIdx.x * blockDim.x + threadIdx.x) >> 6;
    const int nWaves = (gridDim.x * blockDim.x) >> 6;
    const float bj = bias[lane];

    for (int n = wave; n < N_NODES; n += nWaves) {
        const int start = off[n];
        const int deg = cnt[n];
        const int end = start + deg;

        float acc = 0.0f;
        int i = start;
        for (; i + 1 < end; i += 2) {
            int s0 = ssrc[i];
            int s1 = ssrc[i + 1];
            float a = h[(long long)s0 * DIM + lane];
            float b2 = h[(long long)s1 * DIM + lane];
            acc += a + b2;
        }
        if (i < end) {
            int s0 = ssrc[i];
            acc += h[(long long)s0 * DIM + lane];
        }

        float mean_j = acc / fmaxf((float)deg, 1.0f);
        float h_j = h[(long long)n * DIM + lane];

        float o = bj;
#pragma unroll
        for (int k = 0; k < DIM; ++k) {
            o += __shfl(mean_j, k, 64) * sWl[k * DIM + lane];
            o += __shfl(h_j, k, 64) * sWr[k * DIM + lane];
        }
        o = fmaxf(o, 0.0f);
        if (LAYER == 1) {
            float u = u1[(long long)n * DIM + lane];
            o = (u > 0.5f) ? o * 2.0f : 0.0f;
        }
        out[(long long)n * DIM + lane] = o;
    }
}

extern "C" void kernel_launch(void* const* d_in, const int* in_sizes, int n_in,
                              void* d_out, int out_size, void* d_ws, size_t ws_size,
                              hipStream_t stream) {
    const float* x   = (const float*)d_in[0];
    const int*   ei  = (const int*)d_in[1];
    const float* u1  = (const float*)d_in[2];
    const float* W1l = (const float*)d_in[3];
    const float* W1r = (const float*)d_in[4];
    const float* b1  = (const float*)d_in[5];
    const float* W2l = (const float*)d_in[6];
    const float* W2r = (const float*)d_in[7];
    const float* b2  = (const float*)d_in[8];
    float* out = (float*)d_out;

    const int* src = ei;
    const int* dst = ei + N_EDGES;

    // workspace layout
    char* ws = (char*)d_ws;
    auto align256 = [](size_t v) { return (v + 255) & ~(size_t)255; };
    size_t o = 0;
    int* cnt_i  = (int*)(ws + o); o = align256(o + (size_t)N_NODES * 4);
    int* off    = (int*)(ws + o); o = align256(o + (size_t)N_NODES * 4);
    int* cursor = (int*)(ws + o); o = align256(o + (size_t)N_NODES * 4);
    int* bsum   = (int*)(ws + o); o = align256(o + (size_t)NB_SCAN * 4);
    int* ssrc   = (int*)(ws + o); o = align256(o + (size_t)N_EDGES * 4);
    float* h1   = (float*)(ws + o);

    hipMemsetAsync(cnt_i, 0, (size_t)N_NODES * 4, stream);
    hipMemsetAsync(cursor, 0, (size_t)N_NODES * 4, stream);

    const int eBlocks = (N_EDGES + 255) / 256;

    // counting sort (once — shared by both layers)
    hist_kernel<<<eBlocks, 256, 0, stream>>>(dst, cnt_i);
    scan_block_kernel<<<NB_SCAN, 256, 0, stream>>>(cnt_i, off, bsum);
    scan_sums_kernel<<<1, 512, 0, stream>>>(bsum);
    scan_add_kernel<<<NB_SCAN, 256, 0, stream>>>(off, bsum);
    reorder_kernel<<<eBlocks, 256, 0, stream>>>(src, dst, off, cursor, ssrc);

    const int cbBlocks = 2048;
    sage_fused<1><<<cbBlocks, 256, 0, stream>>>(x, ssrc, off, cnt_i, W1l, W1r, b1, u1, h1);
    sage_fused<2><<<cbBlocks, 256, 0, stream>>>(h1, ssrc, off, cnt_i, W2l, W2r, b2, nullptr, out);
}

// Round 3
// 708.607 us; speedup vs baseline: 1.5333x; 1.1834x over previous
//
#include <hip/hip_runtime.h>

#define N_NODES 100000
#define N_EDGES 1200000
#define DIM 64
#define NB_SCAN ((N_NODES + 255) / 256)   // 391

// ---------- counting sort of edges by dst ----------

__global__ __launch_bounds__(256) void hist_kernel(const int* __restrict__ dst,
                                                   int* __restrict__ cnt) {
    int e = blockIdx.x * blockDim.x + threadIdx.x;
    if (e < N_EDGES) atomicAdd(&cnt[dst[e]], 1);
}

// per-256-block exclusive scan of cnt -> cursor; emits block totals
__global__ __launch_bounds__(256) void scan_block_kernel(const int* __restrict__ cnt,
                                                         int* __restrict__ cursor,
                                                         int* __restrict__ bsum) {
    __shared__ int tmp[256];
    int gid = blockIdx.x * 256 + threadIdx.x;
    int v = (gid < N_NODES) ? cnt[gid] : 0;
    tmp[threadIdx.x] = v;
    __syncthreads();
    for (int ofs = 1; ofs < 256; ofs <<= 1) {
        int t = (threadIdx.x >= ofs) ? tmp[threadIdx.x - ofs] : 0;
        __syncthreads();
        tmp[threadIdx.x] += t;
        __syncthreads();
    }
    if (gid < N_NODES) cursor[gid] = tmp[threadIdx.x] - v;
    if (threadIdx.x == 255) bsum[blockIdx.x] = tmp[255];
}

__global__ __launch_bounds__(512) void scan_sums_kernel(int* __restrict__ bsum) {
    __shared__ int tmp[512];
    int v = (threadIdx.x < NB_SCAN) ? bsum[threadIdx.x] : 0;
    tmp[threadIdx.x] = v;
    __syncthreads();
    for (int ofs = 1; ofs < 512; ofs <<= 1) {
        int t = (threadIdx.x >= ofs) ? tmp[threadIdx.x - ofs] : 0;
        __syncthreads();
        tmp[threadIdx.x] += t;
        __syncthreads();
    }
    if (threadIdx.x < NB_SCAN) bsum[threadIdx.x] = tmp[threadIdx.x] - v;
}

__global__ __launch_bounds__(256) void scan_add_kernel(int* __restrict__ cursor,
                                                       const int* __restrict__ bsum) {
    int gid = blockIdx.x * 256 + threadIdx.x;
    if (gid < N_NODES) cursor[gid] += bsum[blockIdx.x];
}

// scatter src into dst-sorted order; cursor ends at off[n]+deg[n] (= end[n])
__global__ __launch_bounds__(256) void reorder_kernel(const int* __restrict__ src,
                                                      const int* __restrict__ dst,
                                                      int* __restrict__ cursor,
                                                      int* __restrict__ ssrc) {
    int e = blockIdx.x * blockDim.x + threadIdx.x;
    if (e < N_EDGES) {
        int t = dst[e];
        int p = atomicAdd(&cursor[t], 1);
        ssrc[p] = src[e];
    }
}

// ---------- aggregate: mean over in-neighbors ----------
// One wave per node; lane j owns feature j. High-MLP: batch-load 64 indices
// with one coalesced load, then 8 independent gathers in flight.
__global__ __launch_bounds__(256) void aggregate_kernel(
    const float* __restrict__ h,
    const int* __restrict__ ssrc,
    const int* __restrict__ cursor,   // end offsets after reorder
    const int* __restrict__ cnt,
    float* __restrict__ mean) {
    const int lane = threadIdx.x & 63;
    const int wave = (blockIdx.x * blockDim.x + threadIdx.x) >> 6;
    if (wave >= N_NODES) return;
    const int n = wave;

    const int end = cursor[n];
    const int deg = cnt[n];
    const int start = end - deg;

    float acc = 0.0f;
    for (int base = start; base < end; base += 64) {
        const int m = min(64, end - base);
        int idx = (lane < m) ? ssrc[base + lane] : 0;
        int i = 0;
        for (; i + 8 <= m; i += 8) {
            float v[8];
#pragma unroll
            for (int k = 0; k < 8; ++k) {
                int s = __shfl(idx, i + k, 64);
                v[k] = h[(size_t)s * DIM + lane];
            }
            acc += ((v[0] + v[1]) + (v[2] + v[3])) + ((v[4] + v[5]) + (v[6] + v[7]));
        }
        for (; i < m; ++i) {
            int s = __shfl(idx, i, 64);
            acc += h[(size_t)s * DIM + lane];
        }
    }
    mean[(size_t)n * DIM + lane] = acc / fmaxf((float)deg, 1.0f);
}

// ---------- combine: out = act(mean@Wl + h@Wr + b) ----------
template <int LAYER>
__global__ __launch_bounds__(256) void combine_kernel(
    const float* __restrict__ mean,
    const float* __restrict__ hin,
    const float* __restrict__ Wl,
    const float* __restrict__ Wr,
    const float* __restrict__ bias,
    const float* __restrict__ u1,
    float* __restrict__ out) {
    __shared__ float sWl[DIM * DIM];
    __shared__ float sWr[DIM * DIM];
    for (int i = threadIdx.x; i < DIM * DIM; i += blockDim.x) {
        sWl[i] = Wl[i];
        sWr[i] = Wr[i];
    }
    __syncthreads();

    const int lane = threadIdx.x & 63;
    const int wave = (blockIdx.x * blockDim.x + threadIdx.x) >> 6;
    const int nWaves = (gridDim.x * blockDim.x) >> 6;
    const float bj = bias[lane];

    for (int n = wave; n < N_NODES; n += nWaves) {
        const size_t base = (size_t)n * DIM;
        float mean_j = mean[base + lane];
        float h_j = hin[base + lane];
        float o = bj;
#pragma unroll
        for (int k = 0; k < DIM; ++k) {
            o += __shfl(mean_j, k, 64) * sWl[k * DIM + lane];
            o += __shfl(h_j, k, 64) * sWr[k * DIM + lane];
        }
        o = fmaxf(o, 0.0f);
        if (LAYER == 1) {
            float u = u1[base + lane];
            o = (u > 0.5f) ? o * 2.0f : 0.0f;
        }
        out[base + lane] = o;
    }
}

extern "C" void kernel_launch(void* const* d_in, const int* in_sizes, int n_in,
                              void* d_out, int out_size, void* d_ws, size_t ws_size,
                              hipStream_t stream) {
    const float* x   = (const float*)d_in[0];
    const int*   ei  = (const int*)d_in[1];
    const float* u1  = (const float*)d_in[2];
    const float* W1l = (const float*)d_in[3];
    const float* W1r = (const float*)d_in[4];
    const float* b1  = (const float*)d_in[5];
    const float* W2l = (const float*)d_in[6];
    const float* W2r = (const float*)d_in[7];
    const float* b2  = (const float*)d_in[8];
    float* out = (float*)d_out;

    const int* src = ei;
    const int* dst = ei + N_EDGES;

    // workspace layout (h1 lives in d_out; combine<2> reads row n then
    // overwrites row n — no cross-row reads of hin in combine)
    char* ws = (char*)d_ws;
    auto align256 = [](size_t v) { return (v + 255) & ~(size_t)255; };
    size_t o = 0;
    int* cnt    = (int*)(ws + o); o = align256(o + (size_t)N_NODES * 4);
    int* cursor = (int*)(ws + o); o = align256(o + (size_t)N_NODES * 4);
    int* bsum   = (int*)(ws + o); o = align256(o + (size_t)NB_SCAN * 4);
    int* ssrc   = (int*)(ws + o); o = align256(o + (size_t)N_EDGES * 4);
    float* mean = (float*)(ws + o);
    float* h1   = out;

    hipMemsetAsync(cnt, 0, (size_t)N_NODES * 4, stream);

    const int eBlocks = (N_EDGES + 255) / 256;
    const int aggBlocks = (N_NODES + 3) / 4;   // one wave per node, 4 waves/block
    const int cbBlocks = 2048;

    // counting sort (once — shared by both layers)
    hist_kernel<<<eBlocks, 256, 0, stream>>>(dst, cnt);
    scan_block_kernel<<<NB_SCAN, 256, 0, stream>>>(cnt, cursor, bsum);
    scan_sums_kernel<<<1, 512, 0, stream>>>(bsum);
    scan_add_kernel<<<NB_SCAN, 256, 0, stream>>>(cursor, bsum);
    reorder_kernel<<<eBlocks, 256, 0, stream>>>(src, dst, cursor, ssrc);

    // ---- Layer 1 ----
    aggregate_kernel<<<aggBlocks, 256, 0, stream>>>(x, ssrc, cursor, cnt, mean);
    combine_kernel<1><<<cbBlocks, 256, 0, stream>>>(mean, x, W1l, W1r, b1, u1, h1);

    // ---- Layer 2 ----
    aggregate_kernel<<<aggBlocks, 256, 0, stream>>>(h1, ssrc, cursor, cnt, mean);
    combine_kernel<2><<<cbBlocks, 256, 0, stream>>>(mean, h1, W2l, W2r, b2, nullptr, out);
}

// Round 4
// 425.765 us; speedup vs baseline: 2.5520x; 1.6643x over previous
//
#include <hip/hip_runtime.h>
#include <hip/hip_bf16.h>

#define N_NODES 100000
#define N_EDGES 1200000
#define DIM 64
#define NB_SCAN ((N_NODES + 255) / 256)   // 391

static __device__ __forceinline__ unsigned short bf16bits(float f) {
    __hip_bfloat16 h = __float2bfloat16(f);
    return *reinterpret_cast<unsigned short*>(&h);
}
static __device__ __forceinline__ float bf16raw2f(unsigned short s) {
    return __uint_as_float(((unsigned)s) << 16);
}

// ---------- counting sort of edges by dst ----------

__global__ __launch_bounds__(256) void hist_kernel(const int* __restrict__ dst,
                                                   int* __restrict__ cnt) {
    int e = blockIdx.x * blockDim.x + threadIdx.x;
    if (e < N_EDGES) atomicAdd(&cnt[dst[e]], 1);
}

__global__ __launch_bounds__(256) void scan_block_kernel(const int* __restrict__ cnt,
                                                         int* __restrict__ cursor,
                                                         int* __restrict__ bsum) {
    __shared__ int tmp[256];
    int gid = blockIdx.x * 256 + threadIdx.x;
    int v = (gid < N_NODES) ? cnt[gid] : 0;
    tmp[threadIdx.x] = v;
    __syncthreads();
    for (int ofs = 1; ofs < 256; ofs <<= 1) {
        int t = (threadIdx.x >= ofs) ? tmp[threadIdx.x - ofs] : 0;
        __syncthreads();
        tmp[threadIdx.x] += t;
        __syncthreads();
    }
    if (gid < N_NODES) cursor[gid] = tmp[threadIdx.x] - v;
    if (threadIdx.x == 255) bsum[blockIdx.x] = tmp[255];
}

__global__ __launch_bounds__(512) void scan_sums_kernel(int* __restrict__ bsum) {
    __shared__ int tmp[512];
    int v = (threadIdx.x < NB_SCAN) ? bsum[threadIdx.x] : 0;
    tmp[threadIdx.x] = v;
    __syncthreads();
    for (int ofs = 1; ofs < 512; ofs <<= 1) {
        int t = (threadIdx.x >= ofs) ? tmp[threadIdx.x - ofs] : 0;
        __syncthreads();
        tmp[threadIdx.x] += t;
        __syncthreads();
    }
    if (threadIdx.x < NB_SCAN) bsum[threadIdx.x] = tmp[threadIdx.x] - v;
}

__global__ __launch_bounds__(256) void scan_add_kernel(int* __restrict__ cursor,
                                                       const int* __restrict__ bsum) {
    int gid = blockIdx.x * 256 + threadIdx.x;
    if (gid < N_NODES) cursor[gid] += bsum[blockIdx.x];
}

// scatter src into dst-sorted order; cursor ends at end[n] = off[n]+deg[n]
__global__ __launch_bounds__(256) void reorder_kernel(const int* __restrict__ src,
                                                      const int* __restrict__ dst,
                                                      int* __restrict__ cursor,
                                                      int* __restrict__ ssrc) {
    int e = blockIdx.x * blockDim.x + threadIdx.x;
    if (e < N_EDGES) {
        int t = dst[e];
        int p = atomicAdd(&cursor[t], 1);
        ssrc[p] = src[e];
    }
}

// ---------- f32 -> bf16 table conversion ----------
__global__ __launch_bounds__(256) void cvt_bf16_kernel(const float* __restrict__ in,
                                                       unsigned short* __restrict__ out) {
    int i = blockIdx.x * blockDim.x + threadIdx.x;   // quads of elements
    const int total = N_NODES * DIM / 4;
    if (i >= total) return;
    float4 v = ((const float4*)in)[i];
    ushort4 p;
    p.x = bf16bits(v.x); p.y = bf16bits(v.y); p.z = bf16bits(v.z); p.w = bf16bits(v.w);
    ((ushort4*)out)[i] = p;
}

// ---------- aggregate: mean over in-neighbors (one wave per node) ----------
__global__ __launch_bounds__(256) void aggregate_f32_kernel(
    const float* __restrict__ h,
    const int* __restrict__ ssrc,
    const int* __restrict__ cursor,   // end offsets
    const int* __restrict__ cnt,
    float* __restrict__ mean) {
    const int lane = threadIdx.x & 63;
    const int wave = (blockIdx.x * blockDim.x + threadIdx.x) >> 6;
    if (wave >= N_NODES) return;
    const int n = wave;
    const int end = cursor[n];
    const int deg = cnt[n];
    const int start = end - deg;

    float acc = 0.0f;
    for (int base = start; base < end; base += 64) {
        const int m = min(64, end - base);
        int idx = (lane < m) ? ssrc[base + lane] : 0;
        int i = 0;
        for (; i + 8 <= m; i += 8) {
            float v[8];
#pragma unroll
            for (int k = 0; k < 8; ++k) {
                int s = __shfl(idx, i + k, 64);
                v[k] = h[(size_t)s * DIM + lane];
            }
            acc += ((v[0] + v[1]) + (v[2] + v[3])) + ((v[4] + v[5]) + (v[6] + v[7]));
        }
        for (; i < m; ++i) {
            int s = __shfl(idx, i, 64);
            acc += h[(size_t)s * DIM + lane];
        }
    }
    mean[(size_t)n * DIM + lane] = acc / fmaxf((float)deg, 1.0f);
}

__global__ __launch_bounds__(256) void aggregate_bf16_kernel(
    const unsigned short* __restrict__ hb,
    const int* __restrict__ ssrc,
    const int* __restrict__ cursor,
    const int* __restrict__ cnt,
    float* __restrict__ mean) {
    const int lane = threadIdx.x & 63;
    const int wave = (blockIdx.x * blockDim.x + threadIdx.x) >> 6;
    if (wave >= N_NODES) return;
    const int n = wave;
    const int end = cursor[n];
    const int deg = cnt[n];
    const int start = end - deg;

    float acc = 0.0f;
    for (int base = start; base < end; base += 64) {
        const int m = min(64, end - base);
        int idx = (lane < m) ? ssrc[base + lane] : 0;
        int i = 0;
        for (; i + 8 <= m; i += 8) {
            float v[8];
#pragma unroll
            for (int k = 0; k < 8; ++k) {
                int s = __shfl(idx, i + k, 64);
                v[k] = bf16raw2f(hb[(size_t)s * DIM + lane]);
            }
            acc += ((v[0] + v[1]) + (v[2] + v[3])) + ((v[4] + v[5]) + (v[6] + v[7]));
        }
        for (; i < m; ++i) {
            int s = __shfl(idx, i, 64);
            acc += bf16raw2f(hb[(size_t)s * DIM + lane]);
        }
    }
    mean[(size_t)n * DIM + lane] = acc / fmaxf((float)deg, 1.0f);
}

// ---------- combine: out = act(mean@Wl + h@Wr + b) ----------
// lane = node; wave = 16-wide output slice (j0 wave-uniform via readfirstlane
// -> all W/bias accesses are scalar s_loads; inner loop is pure v_fmac).
template <int LAYER>
__global__ __launch_bounds__(256) void combine_kernel(
    const float* __restrict__ mean,
    const float* __restrict__ hf,             // LAYER==1: x (f32)
    const unsigned short* __restrict__ hb,    // LAYER==2: h1 bf16
    const float* __restrict__ Wl,
    const float* __restrict__ Wr,
    const float* __restrict__ bias,
    const float* __restrict__ u1,
    float* __restrict__ outf,                 // LAYER==2: final output
    unsigned short* __restrict__ outb) {      // LAYER==1: h1 bf16
    const int lane = threadIdx.x & 63;
    const int wv = __builtin_amdgcn_readfirstlane((int)(threadIdx.x >> 6));
    const int j0 = wv * 16;
    const int n0 = blockIdx.x * 64 + lane;
    const int n = (n0 < N_NODES) ? n0 : (N_NODES - 1);
    const bool ok = (n0 < N_NODES);

    float acc[16];
#pragma unroll
    for (int j = 0; j < 16; ++j) acc[j] = bias[j0 + j];

    // mean @ Wl
    const float* mrow = mean + (size_t)n * DIM;
#pragma unroll
    for (int kc = 0; kc < DIM; kc += 4) {
        float4 am = *(const float4*)(mrow + kc);
        float a4[4] = {am.x, am.y, am.z, am.w};
#pragma unroll
        for (int kk = 0; kk < 4; ++kk) {
#pragma unroll
            for (int j = 0; j < 16; ++j)
                acc[j] += a4[kk] * Wl[(kc + kk) * DIM + j0 + j];
        }
    }

    // h @ Wr
    if (LAYER == 1) {
        const float* hrow = hf + (size_t)n * DIM;
#pragma unroll
        for (int kc = 0; kc < DIM; kc += 4) {
            float4 ah = *(const float4*)(hrow + kc);
            float a4[4] = {ah.x, ah.y, ah.z, ah.w};
#pragma unroll
            for (int kk = 0; kk < 4; ++kk) {
#pragma unroll
                for (int j = 0; j < 16; ++j)
                    acc[j] += a4[kk] * Wr[(kc + kk) * DIM + j0 + j];
            }
        }
    } else {
        const unsigned short* hrow = hb + (size_t)n * DIM;
#pragma unroll
        for (int kc = 0; kc < DIM; kc += 8) {
            union { uint4 q; unsigned short s[8]; } u;
            u.q = *(const uint4*)(hrow + kc);
#pragma unroll
            for (int kk = 0; kk < 8; ++kk) {
                float a = bf16raw2f(u.s[kk]);
#pragma unroll
                for (int j = 0; j < 16; ++j)
                    acc[j] += a * Wr[(kc + kk) * DIM + j0 + j];
            }
        }
    }

    // ReLU (+ dropout on layer 1)
#pragma unroll
    for (int j = 0; j < 16; ++j) acc[j] = fmaxf(acc[j], 0.0f);

    if (LAYER == 1) {
        const float* urow = u1 + (size_t)n * DIM + j0;
#pragma unroll
        for (int jc = 0; jc < 16; jc += 4) {
            float4 u4 = *(const float4*)(urow + jc);
            float uv[4] = {u4.x, u4.y, u4.z, u4.w};
#pragma unroll
            for (int t = 0; t < 4; ++t)
                acc[jc + t] = (uv[t] > 0.5f) ? acc[jc + t] * 2.0f : 0.0f;
        }
        if (ok) {
#pragma unroll
            for (int jc = 0; jc < 16; jc += 4) {
                ushort4 p;
                p.x = bf16bits(acc[jc]);
                p.y = bf16bits(acc[jc + 1]);
                p.z = bf16bits(acc[jc + 2]);
                p.w = bf16bits(acc[jc + 3]);
                *(ushort4*)(outb + (size_t)n * DIM + j0 + jc) = p;
            }
        }
    } else {
        if (ok) {
#pragma unroll
            for (int jc = 0; jc < 16; jc += 4) {
                float4 v;
                v.x = acc[jc]; v.y = acc[jc + 1]; v.z = acc[jc + 2]; v.w = acc[jc + 3];
                *(float4*)(outf + (size_t)n * DIM + j0 + jc) = v;
            }
        }
    }
}

extern "C" void kernel_launch(void* const* d_in, const int* in_sizes, int n_in,
                              void* d_out, int out_size, void* d_ws, size_t ws_size,
                              hipStream_t stream) {
    const float* x   = (const float*)d_in[0];
    const int*   ei  = (const int*)d_in[1];
    const float* u1  = (const float*)d_in[2];
    const float* W1l = (const float*)d_in[3];
    const float* W1r = (const float*)d_in[4];
    const float* b1  = (const float*)d_in[5];
    const float* W2l = (const float*)d_in[6];
    const float* W2r = (const float*)d_in[7];
    const float* b2  = (const float*)d_in[8];
    float* out = (float*)d_out;

    const int* src = ei;
    const int* dst = ei + N_EDGES;

    char* ws = (char*)d_ws;
    auto align256 = [](size_t v) { return (v + 255) & ~(size_t)255; };
    size_t o = 0;
    int* cnt    = (int*)(ws + o); o = align256(o + (size_t)N_NODES * 4);
    int* cursor = (int*)(ws + o); o = align256(o + (size_t)N_NODES * 4);
    int* bsum   = (int*)(ws + o); o = align256(o + (size_t)NB_SCAN * 4);
    int* ssrc   = (int*)(ws + o); o = align256(o + (size_t)N_EDGES * 4);
    float* mean = (float*)(ws + o); o = align256(o + (size_t)N_NODES * DIM * 4);
    unsigned short* h1b = (unsigned short*)(ws + o); o = align256(o + (size_t)N_NODES * DIM * 2);
    unsigned short* xb  = (unsigned short*)(ws + o);
    size_t need_xb = o + (size_t)N_NODES * DIM * 2;
    const bool useXb = (ws_size >= need_xb);   // ws_size is constant across calls

    hipMemsetAsync(cnt, 0, (size_t)N_NODES * 4, stream);

    const int eBlocks = (N_EDGES + 255) / 256;
    const int aggBlocks = (N_NODES + 3) / 4;
    const int cbBlocks = (N_NODES + 63) / 64;   // 1563
    const int cvBlocks = (N_NODES * DIM / 4 + 255) / 256;

    // counting sort (once — shared by both layers)
    hist_kernel<<<eBlocks, 256, 0, stream>>>(dst, cnt);
    scan_block_kernel<<<NB_SCAN, 256, 0, stream>>>(cnt, cursor, bsum);
    scan_sums_kernel<<<1, 512, 0, stream>>>(bsum);
    scan_add_kernel<<<NB_SCAN, 256, 0, stream>>>(cursor, bsum);
    reorder_kernel<<<eBlocks, 256, 0, stream>>>(src, dst, cursor, ssrc);

    // ---- Layer 1 ----
    if (useXb) {
        cvt_bf16_kernel<<<cvBlocks, 256, 0, stream>>>(x, xb);
        aggregate_bf16_kernel<<<aggBlocks, 256, 0, stream>>>(xb, ssrc, cursor, cnt, mean);
    } else {
        aggregate_f32_kernel<<<aggBlocks, 256, 0, stream>>>(x, ssrc, cursor, cnt, mean);
    }
    combine_kernel<1><<<cbBlocks, 256, 0, stream>>>(mean, x, nullptr, W1l, W1r, b1, u1,
                                                    nullptr, h1b);

    // ---- Layer 2 ----
    aggregate_bf16_kernel<<<aggBlocks, 256, 0, stream>>>(h1b, ssrc, cursor, cnt, mean);
    combine_kernel<2><<<cbBlocks, 256, 0, stream>>>(mean, nullptr, h1b, W2l, W2r, b2, nullptr,
                                                    out, nullptr);
}